// Round 11
// baseline (245.626 us; speedup 1.0000x reference)
//
#include <hip/hip_runtime.h>
#include <math.h>

#define N_PTS   8192
#define KNN     30
#define CAPG    104     // max stored candidates per group
#define STR     112     // LDS row stride in u64 (16B-aligned; 4 sentinel slots)
#define GROUPS  8       // queries per block
#define BLOCK   128     // 2 waves per block
#define NXB     8       // x slabs (primary sort key)
#define NZ      64
#define NY      64
#define NBKT3   (NXB * NZ * NY)   // 32768 buckets
#define CLO     -4.0f
#define CSC     8.0f
#define INVCSC  0.125f
#define XLO     -4.0f   // x slab width 1.0
#define LAMBDA  40.0
#define RBINS   2048
#define RWMAX   32.0f
#define RSCALE  ((float)RBINS / RWMAX)

// ws: S f4[32768]@0 (524288) | O i32[32768]@524288 (131072) |
//     bstart i32[4*32769]@655360 (524304) | ghist i32[4*32768]@1179664 (524288) |
//     R2T f32[2048]@1703952 (8192)
#define WS_S   0
#define WS_O   524288
#define WS_BS  655360
#define WS_GH  1179664
#define WS_R2  1703952
#define BSTR   (NBKT3 + 1)

__device__ __forceinline__ int clampi(int v, int lo, int hi) {
    return v < lo ? lo : (v > hi ? hi : v);
}
__device__ __forceinline__ int bucket3_of(float px, float pz, float py) {
    int xb = clampi((int)floorf(px - XLO), 0, NXB - 1);
    int zb = clampi((int)floorf((pz - CLO) * CSC), 0, NZ - 1);
    int yb = clampi((int)floorf((py - CLO) * CSC), 0, NY - 1);
    return (xb << 12) | (zb << 6) | yb;
}

// ---------------------------------------------------------------------------
// Prep A (r1-proven pattern): full-chip. Copy x -> out ch0..2, histogram
// (x,z,y) buckets via global atomics (ghist pre-zeroed). 128 x 256.
// ---------------------------------------------------------------------------
__global__ __launch_bounds__(256) void prep_hist_kernel(const float* __restrict__ x,
                                                        float* __restrict__ out,
                                                        int* __restrict__ ghist) {
    const int i = blockIdx.x * 256 + threadIdx.x;     // 0..32767
    const int b = i >> 13;
    const int p = i & (N_PTS - 1);
    const float* xb = x + (size_t)b * 3 * N_PTS;
    float* ob = out + (size_t)b * 6 * N_PTS;
    float px = xb[p], py = xb[N_PTS + p], pz = xb[2 * N_PTS + p];
    ob[p]             = px;
    ob[N_PTS + p]     = py;
    ob[2 * N_PTS + p] = pz;
    atomicAdd(&ghist[(b << 15) + bucket3_of(px, pz, py)], 1);
}

// ---------------------------------------------------------------------------
// Prep B: per-batch exclusive scan of 32768-bucket histogram.
// 4 blocks x 1024 threads; thread t owns 32 buckets [32t, 32t+32).
// ---------------------------------------------------------------------------
__global__ __launch_bounds__(1024) void prep_scan_kernel(const int* __restrict__ ghist,
                                                         int* __restrict__ bstart,
                                                         int* __restrict__ gcur) {
    __shared__ int wsum[16];
    const int b = blockIdx.x;
    const int t = threadIdx.x;
    const int wid = t >> 6, lane = t & 63;
    const int* gh = ghist + (b << 15);

    int s = 0;
    #pragma unroll
    for (int k = 0; k < 32; ++k) s += gh[32 * t + k];
    int incl = s;
    #pragma unroll
    for (int off = 1; off < 64; off <<= 1) {
        int v = __shfl_up(incl, off);
        if (lane >= off) incl += v;
    }
    if (lane == 63) wsum[wid] = incl;
    __syncthreads();
    if (t == 0) {
        int run = 0;
        #pragma unroll
        for (int k = 0; k < 16; ++k) { int v = wsum[k]; wsum[k] = run; run += v; }
    }
    __syncthreads();
    int run = wsum[wid] + (incl - s);     // exclusive prefix for this thread's range
    int* bsb = bstart + b * BSTR;
    int* gc  = gcur + (b << 15);
    #pragma unroll
    for (int k = 0; k < 32; ++k) {
        int idx = 32 * t + k;
        bsb[idx] = run;
        gc[idx]  = run;
        run += gh[idx];
    }
    if (t == 1023) bsb[NBKT3] = N_PTS;
}

// ---------------------------------------------------------------------------
// Prep C: full-chip scatter via global bucket cursors (intra-bucket order is
// nondeterministic; selection is order-independent -- r1/r2-proven). 128x256.
// ---------------------------------------------------------------------------
__global__ __launch_bounds__(256) void prep_scatter_kernel(const float* __restrict__ x,
                                                           float4* __restrict__ S,
                                                           int* __restrict__ O,
                                                           int* __restrict__ gcur) {
    const int i = blockIdx.x * 256 + threadIdx.x;     // 0..32767
    const int b = i >> 13;
    const int p = i & (N_PTS - 1);
    const float* xb = x + (size_t)b * 3 * N_PTS;
    float px = xb[p], py = xb[N_PTS + p], pz = xb[2 * N_PTS + p];
    int bk = bucket3_of(px, pz, py);
    int dst = atomicAdd(&gcur[(b << 15) + bk], 1);
    float xx = __fadd_rn(__fadd_rn(__fmul_rn(px, px), __fmul_rn(py, py)),
                         __fmul_rn(pz, pz));
    S[((size_t)b << 13) + dst] = make_float4(px, py, pz, xx);
    O[((size_t)b << 13) + dst] = p;
}

// ---------------------------------------------------------------------------
// Main (r10 body + x-slab pruning): 16 lanes/query, 8 queries/block.
// Table radius; scan over (x-slab, z-row) with circular residual pruning in
// BOTH x and z (edge bins use infinite outer edges -> conservative); y-span
// contiguous per (xb,zb). Hit set per query is exactly preserved vs the
// 2D scan -> identical keys -> identical top-30. Rank: 4-wide vector reads.
// ---------------------------------------------------------------------------
__global__ __launch_bounds__(BLOCK, 6) void knn_normal_kernel(const float4* __restrict__ S,
                                                              const int* __restrict__ O,
                                                              const int* __restrict__ bstart,
                                                              const float* __restrict__ R2T,
                                                              float* __restrict__ out) {
    __shared__ __align__(16) unsigned long long ldk[GROUPS * STR];

    const int t    = threadIdx.x;
    const int l16  = t & 15;
    const int g    = t >> 4;
    const int gsh  = (t & 63) & ~15;
    const int qblk = (blockIdx.x * 1031) & 4095;   // bijective swizzle
    const int qid  = qblk * GROUPS + g;
    const int b    = qid >> 13;
    const int pos  = qid & (N_PTS - 1);
    const float4* __restrict__ P  = S + ((size_t)b << 13);
    const int*    __restrict__ Ob = O + ((size_t)b << 13);
    const int*    __restrict__ bs = bstart + b * BSTR;
    const float4 qp = P[pos];
    const int    oi = Ob[pos];

    unsigned long long* __restrict__ ldg = ldk + g * STR;

    const int rbin = min((int)(qp.w * RSCALE), RBINS - 1);
    float r2 = R2T[rbin];

    int  cnt = 0;
    bool active = true;

    for (;;) {
        if (active) {
            cnt = 0;
            float w  = __fmaf_rn(sqrtf(r2), 1.002f, 1e-3f);   // w > sqrt(r2)
            float w2 = __fmul_rn(w, w);
            int xlo = clampi((int)floorf(qp.x - w - XLO), 0, NXB - 1);
            int xhi = clampi((int)floorf(qp.x + w - XLO), 0, NXB - 1);
            int zlo = clampi((int)floorf((qp.z - w - CLO) * CSC), 0, NZ - 1);
            int zhi = clampi((int)floorf((qp.z + w - CLO) * CSC), 0, NZ - 1);
            for (int xb = xlo; xb <= xhi; ++xb) {
                // conservative distance from qx to x-slab (edge slabs open-ended)
                float xl = XLO + (float)xb;
                float dxl = (xb == 0)       ? -1e30f : xl - qp.x;
                float dxh = (xb == NXB - 1) ? -1e30f : qp.x - (xl + 1.0f);
                float dxr = fmaxf(fmaxf(dxl, dxh), 0.0f) * 0.999f;
                float rem = __fmaf_rn(-dxr, dxr, w2);
                if (rem <= 0.0f) continue;
                const int xoff = xb << 12;
                for (int zb = zlo; zb <= zhi; ++zb) {
                    float z0  = CLO + (float)zb * INVCSC;
                    float dzl = (zb == 0)      ? -1e30f : z0 - qp.z;
                    float dzh = (zb == NZ - 1) ? -1e30f : qp.z - (z0 + INVCSC);
                    float dzr = fmaxf(fmaxf(dzl, dzh), 0.0f) * 0.999f;
                    float hw2 = __fmaf_rn(-dzr, dzr, rem);
                    if (hw2 <= 0.0f) continue;
                    float hw  = __fmaf_rn(sqrtf(hw2), 1.001f, 1e-4f);
                    int ylo = clampi((int)floorf((qp.y - hw - CLO) * CSC), 0, NY - 1);
                    int yhi = clampi((int)floorf((qp.y + hw - CLO) * CSC), 0, NY - 1);
                    int lo = bs[xoff + (zb << 6) + ylo];
                    int hi = bs[xoff + (zb << 6) + yhi + 1];
                    int nfull = (hi - lo) >> 5;        // full chunks: no bounds checks
                    for (int s = 0; s < nfull; ++s) {
                        int j1  = lo + (s << 5) + l16;
                        int j2  = j1 + 16;
                        float4 p1 = P[j1];
                        float4 p2 = P[j2];
                        float mm1 = __fmaf_rn(qp.z, p1.z, __fmaf_rn(qp.y, p1.y, __fmul_rn(qp.x, p1.x)));
                        float d1  = __fsub_rn(__fadd_rn(qp.w, p1.w), __fmul_rn(2.0f, mm1));
                        float mm2 = __fmaf_rn(qp.z, p2.z, __fmaf_rn(qp.y, p2.y, __fmul_rn(qp.x, p2.x)));
                        float d2  = __fsub_rn(__fadd_rn(qp.w, p2.w), __fmul_rn(2.0f, mm2));
                        bool hit1 = d1 <= r2;
                        bool hit2 = d2 <= r2;
                        unsigned long long m1 = __ballot(hit1);
                        unsigned sub1 = (unsigned)((m1 >> gsh) & 0xFFFFull);
                        if (hit1) {
                            int slot = cnt + __popc(sub1 & ((1u << l16) - 1u));
                            if (slot < CAPG) {
                                unsigned u = __float_as_uint(d1);
                                u = (u & 0x80000000u) ? ~u : (u | 0x80000000u);
                                ldg[slot] = ((unsigned long long)u << 28) | (unsigned long long)j1;
                            }
                        }
                        cnt += __popc(sub1);
                        unsigned long long m2 = __ballot(hit2);
                        unsigned sub2 = (unsigned)((m2 >> gsh) & 0xFFFFull);
                        if (hit2) {
                            int slot = cnt + __popc(sub2 & ((1u << l16) - 1u));
                            if (slot < CAPG) {
                                unsigned u = __float_as_uint(d2);
                                u = (u & 0x80000000u) ? ~u : (u | 0x80000000u);
                                ldg[slot] = ((unsigned long long)u << 28) | (unsigned long long)j2;
                            }
                        }
                        cnt += __popc(sub2);
                    }
                    if ((hi - lo) & 31) {              // remainder: bounds-checked
                        int j1  = lo + (nfull << 5) + l16;
                        int j2  = j1 + 16;
                        int jc1 = j1 < hi ? j1 : hi - 1;
                        int jc2 = j2 < hi ? j2 : hi - 1;
                        float4 p1 = P[jc1];
                        float4 p2 = P[jc2];
                        float mm1 = __fmaf_rn(qp.z, p1.z, __fmaf_rn(qp.y, p1.y, __fmul_rn(qp.x, p1.x)));
                        float d1  = __fsub_rn(__fadd_rn(qp.w, p1.w), __fmul_rn(2.0f, mm1));
                        float mm2 = __fmaf_rn(qp.z, p2.z, __fmaf_rn(qp.y, p2.y, __fmul_rn(qp.x, p2.x)));
                        float d2  = __fsub_rn(__fadd_rn(qp.w, p2.w), __fmul_rn(2.0f, mm2));
                        bool hit1 = (j1 < hi) && (d1 <= r2);
                        bool hit2 = (j2 < hi) && (d2 <= r2);
                        unsigned long long m1 = __ballot(hit1);
                        unsigned sub1 = (unsigned)((m1 >> gsh) & 0xFFFFull);
                        if (hit1) {
                            int slot = cnt + __popc(sub1 & ((1u << l16) - 1u));
                            if (slot < CAPG) {
                                unsigned u = __float_as_uint(d1);
                                u = (u & 0x80000000u) ? ~u : (u | 0x80000000u);
                                ldg[slot] = ((unsigned long long)u << 28) | (unsigned long long)jc1;
                            }
                        }
                        cnt += __popc(sub1);
                        unsigned long long m2 = __ballot(hit2);
                        unsigned sub2 = (unsigned)((m2 >> gsh) & 0xFFFFull);
                        if (hit2) {
                            int slot = cnt + __popc(sub2 & ((1u << l16) - 1u));
                            if (slot < CAPG) {
                                unsigned u = __float_as_uint(d2);
                                u = (u & 0x80000000u) ? ~u : (u | 0x80000000u);
                                ldg[slot] = ((unsigned long long)u << 28) | (unsigned long long)jc2;
                            }
                        }
                        cnt += __popc(sub2);
                    }
                }
            }
        }
        bool bad = active && (cnt < KNN || cnt > CAPG);
        if (__ballot(bad) == 0ULL) break;         // wave-uniform exit
        active = bad;
        if (active) r2 = (cnt < KNN) ? r2 * 1.6f : r2 * 0.82f;
    }

    // sentinels for the 4-wide rank loop
    if (l16 < 4) ldg[cnt + l16] = ~0ULL;

    // fill orig-idx field (bits 14..27) so u64 order == lex (d, orig idx)
    for (int k = l16; k < cnt; k += 16) {
        unsigned long long key = ldg[k];
        int jc = (int)(key & 0x3FFFull);
        ldg[k] = (key & ~0x0FFFFFFFull) | ((unsigned long long)Ob[jc] << 14) | (unsigned long long)jc;
    }
    __builtin_amdgcn_wave_barrier();
    asm volatile("s_waitcnt lgkmcnt(0)" ::: "memory");

    // ---- stable top-30: rank by u64 key, 4-wide vector LDS reads ----
    const double qx = (double)qp.x, qy = (double)qp.y, qz = (double)qp.z;
    double sx = 0.0, sy = 0.0, sz = 0.0;
    double sxx = 0.0, sxy = 0.0, sxz = 0.0, syy = 0.0, syz = 0.0, szz = 0.0;

    const ulonglong2* __restrict__ ldg2 = (const ulonglong2*)ldg;
    const int cntr = (cnt + 3) >> 2;

    for (int k = l16; k < cnt; k += 16) {
        unsigned long long key = ldg[k];
        int rank = 0;
        for (int u = 0; u < cntr; ++u) {
            ulonglong2 a = ldg2[2 * u];
            ulonglong2 c = ldg2[2 * u + 1];
            rank += (a.x < key) ? 1 : 0;
            rank += (a.y < key) ? 1 : 0;
            rank += (c.x < key) ? 1 : 0;
            rank += (c.y < key) ? 1 : 0;
        }
        if (rank < KNN) {
            float4 p = P[(int)(key & 0x3FFFull)];
            double ax = (double)p.x - qx, ay = (double)p.y - qy, az = (double)p.z - qz;
            sx += ax; sy += ay; sz += az;
            sxx = fma(ax, ax, sxx); sxy = fma(ax, ay, sxy); sxz = fma(ax, az, sxz);
            syy = fma(ay, ay, syy); syz = fma(ay, az, syz); szz = fma(az, az, szz);
        }
    }

    #pragma unroll
    for (int off = 1; off < 16; off <<= 1) {
        sx  += __shfl_xor(sx,  off, 16); sy  += __shfl_xor(sy,  off, 16); sz  += __shfl_xor(sz,  off, 16);
        sxx += __shfl_xor(sxx, off, 16); sxy += __shfl_xor(sxy, off, 16); sxz += __shfl_xor(sxz, off, 16);
        syy += __shfl_xor(syy, off, 16); syz += __shfl_xor(syz, off, 16); szz += __shfl_xor(szz, off, 16);
    }

    if (l16 == 0) {
        const double kinv = 1.0 / (double)KNN;
        double m00 = sxx - sx * sx * kinv;
        double m11 = syy - sy * sy * kinv;
        double m22 = szz - sz * sz * kinv;
        double m01 = sxy - sx * sy * kinv;
        double m02 = sxz - sx * sz * kinv;
        double m12 = syz - sy * sz * kinv;

        double nx = 1.0, ny = 0.0, nz = 0.0;
        double q3 = (m00 + m11 + m22) / 3.0;
        double p1 = m01 * m01 + m02 * m02 + m12 * m12;
        double d00 = m00 - q3, d11 = m11 - q3, d22 = m22 - q3;
        double p2 = d00 * d00 + d11 * d11 + d22 * d22 + 2.0 * p1;
        if (p2 > 1e-280) {
            double pp = sqrt(p2 / 6.0);
            double ip = 1.0 / pp;
            double b00 = d00 * ip, b11 = d11 * ip, b22 = d22 * ip;
            double b01 = m01 * ip, b02 = m02 * ip, b12 = m12 * ip;
            double detB = b00 * (b11 * b22 - b12 * b12)
                        - b01 * (b01 * b22 - b12 * b02)
                        + b02 * (b01 * b12 - b11 * b02);
            double rr = 0.5 * detB;
            rr = rr < -1.0 ? -1.0 : (rr > 1.0 ? 1.0 : rr);
            double phi = acos(rr) / 3.0;
            double lam = q3 + 2.0 * pp * cos(phi + 2.0943951023931953); // smallest eig
            double a00 = m00 - lam, a11 = m11 - lam, a22 = m22 - lam;
            double v0x = m01 * m12 - m02 * a11, v0y = m02 * m01 - a00 * m12, v0z = a00 * a11 - m01 * m01;
            double v1x = m01 * a22 - m02 * m12, v1y = m02 * m02 - a00 * a22, v1z = a00 * m12 - m01 * m02;
            double v2x = a11 * a22 - m12 * m12, v2y = m12 * m02 - m01 * a22, v2z = m01 * m12 - a11 * m02;
            double n0 = v0x * v0x + v0y * v0y + v0z * v0z;
            double n1 = v1x * v1x + v1y * v1y + v1z * v1z;
            double n2 = v2x * v2x + v2y * v2y + v2z * v2z;
            double bx = v0x, by = v0y, bz = v0z, bn = n0;
            if (n1 > bn) { bx = v1x; by = v1y; bz = v1z; bn = n1; }
            if (n2 > bn) { bx = v2x; by = v2y; bz = v2z; bn = n2; }
            if (bn > 1e-280) {
                double inv = 1.0 / sqrt(bn);
                nx = bx * inv; ny = by * inv; nz = bz * inv;
            }
        }
        double dq = -(qx * nx + qy * ny + qz * nz);
        if (dq < 0.0) { nx = -nx; ny = -ny; nz = -nz; }

        float* ob = out + (size_t)b * 6 * N_PTS;
        ob[3 * N_PTS + oi] = (float)nx;
        ob[4 * N_PTS + oi] = (float)ny;
        ob[5 * N_PTS + oi] = (float)nz;
    }
}

// ---------------------------------------------------------------------------
// Host-side radius table (input-independent; 8 KB async copy per launch).
// ---------------------------------------------------------------------------
static float  g_r2t[RBINS];
static bool   g_r2t_init = false;

static void build_r2t_host() {
    for (int k = 0; k < RBINS; ++k) {
        double wrep = ((double)k + 0.5) * ((double)RWMAX / (double)RBINS);
        double c = sqrt(wrep); if (c < 1e-3) c = 1e-3;
        double rlo = 0.05, rhi = 6.0;
        for (int it = 0; it < 40; ++it) {
            double r = 0.5 * (rlo + rhi);
            double slo = c - r; if (slo < 0.0) slo = 0.0;
            double h = (c + r - slo) * 0.125;
            double f = 0.0;
            for (int l = 0; l <= 8; ++l) {
                double sq = slo + h * (double)l;
                double cs = c - sq;
                double hh = (r * r - cs * cs) * (0.5 / c);
                double cap = 2.0 * sq;
                if (hh > cap) hh = cap;
                if (hh < 0.0) hh = 0.0;
                double wq = (l == 0 || l == 8) ? 1.0 : ((l & 1) ? 4.0 : 2.0);
                f += wq * exp(-0.5 * sq * sq) * sq * hh;
            }
            double lam = 1089.3 * f * h;
            if (lam < (double)LAMBDA) rlo = r; else rhi = r;
        }
        double rad = rhi * 1.02;
        g_r2t[k] = (float)(rad * rad);
    }
}

// ---------------------------------------------------------------------------
extern "C" void kernel_launch(void* const* d_in, const int* in_sizes, int n_in,
                              void* d_out, int out_size, void* d_ws, size_t ws_size,
                              hipStream_t stream) {
    const float* x = (const float*)d_in[0];
    float* out = (float*)d_out;
    char* ws = (char*)d_ws;
    float4* S    = (float4*)(ws + WS_S);
    int*    O    = (int*)(ws + WS_O);
    int*    bsta = (int*)(ws + WS_BS);
    int*    gh   = (int*)(ws + WS_GH);
    float*  r2t  = (float*)(ws + WS_R2);

    if (!g_r2t_init) { build_r2t_host(); g_r2t_init = true; }
    hipMemcpyAsync(r2t, g_r2t, RBINS * sizeof(float), hipMemcpyHostToDevice, stream);
    hipMemsetAsync(gh, 0, 4 * NBKT3 * sizeof(int), stream);

    prep_hist_kernel   <<<dim3(128), dim3(256),  0, stream>>>(x, out, gh);
    prep_scan_kernel   <<<dim3(4),   dim3(1024), 0, stream>>>(gh, bsta, gh /*unused*/ + 0);
    // NOTE: gcur aliases ghist? No -- scan must write cursors separately.
    // Reuse ghist as gcur is safe ONLY after hist is consumed in the same
    // kernel; here scan reads gh and we need separate cursor storage.
    // We place gcur over the R2T-adjacent tail? Simplest: reuse ghist in
    // place (overwrite hist with cursor starts) -- scan reads gh[idx] before
    // writing gc[idx] in the same iteration, and each idx is touched once.
    prep_scatter_kernel<<<dim3(128), dim3(256),  0, stream>>>(x, S, O, gh);
    knn_normal_kernel  <<<dim3(32768 / GROUPS), dim3(BLOCK), 0, stream>>>(S, O, bsta, r2t, out);
}

// Round 12
// 154.087 us; speedup vs baseline: 1.5941x; 1.5941x over previous
//
#include <hip/hip_runtime.h>
#include <math.h>

#define N_PTS   8192
#define KNN     30
#define CAPG    104     // max stored candidates per group
#define STR     112     // LDS row stride in u64 (16B-aligned; 4 sentinel slots)
#define GROUPS  8       // queries per block
#define BLOCK   128     // 2 waves per block
#define NZ      64
#define NY      64
#define NBKT    (NZ * NY)
#define CLO     -4.0f
#define CSC     8.0f
#define INVCSC  0.125f
#define LAMBDA  40.0
#define RBINS   2048
#define RWMAX   32.0f
#define RSCALE  ((float)RBINS / RWMAX)
#define PTHRESH 768     // window size above which the wave gets issue priority

// ws: S f4[32768]@0 | O i32[32768]@524288 | bstart i32[4*4097]@655360 |
//     R2T f32[2048]@720912

__device__ __forceinline__ int clampi(int v, int lo, int hi) {
    return v < lo ? lo : (v > hi ? hi : v);
}
__device__ __forceinline__ int bucket_of(float pz, float py) {
    int zb = clampi((int)floorf((pz - CLO) * CSC), 0, NZ - 1);
    int yb = clampi((int)floorf((py - CLO) * CSC), 0, NY - 1);
    return (zb << 6) | yb;
}

// ---------------------------------------------------------------------------
// Fused prep (r4/r7-proven): one block per batch (1024 threads). LDS hist ->
// in-block scan -> LDS-atomic counting-sort scatter. Copies x into out ch0..2.
// ---------------------------------------------------------------------------
__global__ __launch_bounds__(1024) void prep_kernel(const float* __restrict__ x,
                                                    float4* __restrict__ S,
                                                    int* __restrict__ O,
                                                    int* __restrict__ bstart,
                                                    float* __restrict__ out) {
    __shared__ int hist[NBKT];
    __shared__ int cur[NBKT];
    __shared__ int wsum[16];

    const int b = blockIdx.x;
    const int t = threadIdx.x;
    const int wid = t >> 6, lane = t & 63;
    const float* xb = x + (size_t)b * 3 * N_PTS;
    float* ob = out + (size_t)b * 6 * N_PTS;

    for (int k = t; k < NBKT; k += 1024) hist[k] = 0;
    __syncthreads();

    float px[8], py[8], pz[8];
    int   bk[8];
    #pragma unroll
    for (int u = 0; u < 8; ++u) {
        int i = (u << 10) + t;
        px[u] = xb[i]; py[u] = xb[N_PTS + i]; pz[u] = xb[2 * N_PTS + i];
        bk[u] = bucket_of(pz[u], py[u]);
        atomicAdd(&hist[bk[u]], 1);
        ob[i]             = px[u];
        ob[N_PTS + i]     = py[u];
        ob[2 * N_PTS + i] = pz[u];
    }
    __syncthreads();

    int l0 = hist[4 * t], l1 = hist[4 * t + 1], l2 = hist[4 * t + 2], l3 = hist[4 * t + 3];
    int s = l0 + l1 + l2 + l3;
    int sum = s;
    #pragma unroll
    for (int off = 1; off < 64; off <<= 1) {
        int v = __shfl_up(sum, off);
        if (lane >= off) sum += v;
    }
    if (lane == 63) wsum[wid] = sum;
    __syncthreads();
    if (t == 0) {
        int run = 0;
        #pragma unroll
        for (int k = 0; k < 16; ++k) { int v = wsum[k]; wsum[k] = run; run += v; }
    }
    __syncthreads();
    int base = wsum[wid] + (sum - s);
    int b0 = base, b1 = base + l0, b2 = b1 + l1, b3 = b2 + l2;
    cur[4 * t] = b0; cur[4 * t + 1] = b1; cur[4 * t + 2] = b2; cur[4 * t + 3] = b3;
    int* bsb = bstart + b * (NBKT + 1);
    bsb[4 * t] = b0; bsb[4 * t + 1] = b1; bsb[4 * t + 2] = b2; bsb[4 * t + 3] = b3;
    if (t == 1023) bsb[NBKT] = N_PTS;
    __syncthreads();

    float4* Sb = S + ((size_t)b << 13);
    int*    Ob = O + ((size_t)b << 13);
    #pragma unroll
    for (int u = 0; u < 8; ++u) {
        int dst = atomicAdd(&cur[bk[u]], 1);
        float xx = __fadd_rn(__fadd_rn(__fmul_rn(px[u], px[u]), __fmul_rn(py[u], py[u])),
                             __fmul_rn(pz[u], pz[u]));
        Sb[dst] = make_float4(px[u], py[u], pz[u], xx);
        Ob[dst] = (u << 10) + t;
    }
}

// ---------------------------------------------------------------------------
// Main (r10 body verbatim + wave cost classifier -> s_setprio):
// heavy waves (any query with window > PTHRESH) get CU issue priority so they
// drain with the pack instead of serializing after it. Scheduling-only change;
// candidate set, keys, and all numerics bit-identical to r10.
// ---------------------------------------------------------------------------
__global__ __launch_bounds__(BLOCK, 6) void knn_normal_kernel(const float4* __restrict__ S,
                                                              const int* __restrict__ O,
                                                              const int* __restrict__ bstart,
                                                              const float* __restrict__ R2T,
                                                              float* __restrict__ out) {
    __shared__ __align__(16) unsigned long long ldk[GROUPS * STR];

    const int t    = threadIdx.x;
    const int l16  = t & 15;
    const int g    = t >> 4;
    const int gsh  = (t & 63) & ~15;
    const int qblk = (blockIdx.x * 1031) & 4095;   // bijective swizzle: flatten tail
    const int qid  = qblk * GROUPS + g;
    const int b    = qid >> 13;
    const int pos  = qid & (N_PTS - 1);
    const float4* __restrict__ P  = S + ((size_t)b << 13);
    const int*    __restrict__ Ob = O + ((size_t)b << 13);
    const int*    __restrict__ bs = bstart + b * (NBKT + 1);
    const float4 qp = P[pos];
    const int    oi = Ob[pos];

    unsigned long long* __restrict__ ldg = ldk + g * STR;

    const int rbin = min((int)(qp.w * RSCALE), RBINS - 1);
    float r2 = R2T[rbin];

    // ---- wave cost classifier: heavy waves get scheduler priority ----
    {
        float ww = __fmaf_rn(sqrtf(r2), 1.002f, 1e-3f);
        int zlo = clampi((int)floorf((qp.z - ww - CLO) * CSC), 0, NZ - 1);
        int zhi = clampi((int)floorf((qp.z + ww - CLO) * CSC), 0, NZ - 1);
        int ylo = clampi((int)floorf((qp.y - ww - CLO) * CSC), 0, NY - 1);
        int yhi = clampi((int)floorf((qp.y + ww - CLO) * CSC), 0, NY - 1);
        int tsum = 0;
        for (int zb = zlo + l16; zb <= zhi; zb += 16)
            tsum += bs[(zb << 6) + yhi + 1] - bs[(zb << 6) + ylo];
        tsum += __shfl_xor(tsum, 1, 16); tsum += __shfl_xor(tsum, 2, 16);
        tsum += __shfl_xor(tsum, 4, 16); tsum += __shfl_xor(tsum, 8, 16);
        if (__ballot(tsum > PTHRESH) != 0ULL)
            __builtin_amdgcn_s_setprio(1);
    }

    int  cnt = 0;
    bool active = true;

    for (;;) {
        if (active) {
            cnt = 0;
            float w  = __fmaf_rn(sqrtf(r2), 1.002f, 1e-3f);   // guard band
            float w2 = __fmul_rn(w, w);
            int zlo = clampi((int)floorf((qp.z - w - CLO) * CSC), 0, NZ - 1);
            int zhi = clampi((int)floorf((qp.z + w - CLO) * CSC), 0, NZ - 1);
            for (int zb = zlo; zb <= zhi; ++zb) {
                float z0  = CLO + (float)zb * INVCSC;
                float dzr = fmaxf(fmaxf(z0 - qp.z, qp.z - (z0 + INVCSC)), 0.0f) * 0.999f;
                float hw2 = __fmaf_rn(-dzr, dzr, w2);
                if (hw2 <= 0.0f) continue;
                float hw  = __fmaf_rn(sqrtf(hw2), 1.001f, 1e-4f);
                int ylo = clampi((int)floorf((qp.y - hw - CLO) * CSC), 0, NY - 1);
                int yhi = clampi((int)floorf((qp.y + hw - CLO) * CSC), 0, NY - 1);
                int lo = bs[(zb << 6) + ylo];
                int hi = bs[(zb << 6) + yhi + 1];
                int nfull = (hi - lo) >> 5;        // full chunks: no bounds checks
                for (int s = 0; s < nfull; ++s) {
                    int j1  = lo + (s << 5) + l16;
                    int j2  = j1 + 16;
                    float4 p1 = P[j1];
                    float4 p2 = P[j2];
                    float mm1 = __fmaf_rn(qp.z, p1.z, __fmaf_rn(qp.y, p1.y, __fmul_rn(qp.x, p1.x)));
                    float d1  = __fsub_rn(__fadd_rn(qp.w, p1.w), __fmul_rn(2.0f, mm1));
                    float mm2 = __fmaf_rn(qp.z, p2.z, __fmaf_rn(qp.y, p2.y, __fmul_rn(qp.x, p2.x)));
                    float d2  = __fsub_rn(__fadd_rn(qp.w, p2.w), __fmul_rn(2.0f, mm2));
                    bool hit1 = d1 <= r2;
                    bool hit2 = d2 <= r2;
                    unsigned long long m1 = __ballot(hit1);
                    unsigned sub1 = (unsigned)((m1 >> gsh) & 0xFFFFull);
                    if (hit1) {
                        int slot = cnt + __popc(sub1 & ((1u << l16) - 1u));
                        if (slot < CAPG) {
                            unsigned u = __float_as_uint(d1);
                            u = (u & 0x80000000u) ? ~u : (u | 0x80000000u);
                            ldg[slot] = ((unsigned long long)u << 28) | (unsigned long long)j1;
                        }
                    }
                    cnt += __popc(sub1);
                    unsigned long long m2 = __ballot(hit2);
                    unsigned sub2 = (unsigned)((m2 >> gsh) & 0xFFFFull);
                    if (hit2) {
                        int slot = cnt + __popc(sub2 & ((1u << l16) - 1u));
                        if (slot < CAPG) {
                            unsigned u = __float_as_uint(d2);
                            u = (u & 0x80000000u) ? ~u : (u | 0x80000000u);
                            ldg[slot] = ((unsigned long long)u << 28) | (unsigned long long)j2;
                        }
                    }
                    cnt += __popc(sub2);
                }
                if ((hi - lo) & 31) {              // remainder: bounds-checked
                    int j1  = lo + (nfull << 5) + l16;
                    int j2  = j1 + 16;
                    int jc1 = j1 < hi ? j1 : hi - 1;
                    int jc2 = j2 < hi ? j2 : hi - 1;
                    float4 p1 = P[jc1];
                    float4 p2 = P[jc2];
                    float mm1 = __fmaf_rn(qp.z, p1.z, __fmaf_rn(qp.y, p1.y, __fmul_rn(qp.x, p1.x)));
                    float d1  = __fsub_rn(__fadd_rn(qp.w, p1.w), __fmul_rn(2.0f, mm1));
                    float mm2 = __fmaf_rn(qp.z, p2.z, __fmaf_rn(qp.y, p2.y, __fmul_rn(qp.x, p2.x)));
                    float d2  = __fsub_rn(__fadd_rn(qp.w, p2.w), __fmul_rn(2.0f, mm2));
                    bool hit1 = (j1 < hi) && (d1 <= r2);
                    bool hit2 = (j2 < hi) && (d2 <= r2);
                    unsigned long long m1 = __ballot(hit1);
                    unsigned sub1 = (unsigned)((m1 >> gsh) & 0xFFFFull);
                    if (hit1) {
                        int slot = cnt + __popc(sub1 & ((1u << l16) - 1u));
                        if (slot < CAPG) {
                            unsigned u = __float_as_uint(d1);
                            u = (u & 0x80000000u) ? ~u : (u | 0x80000000u);
                            ldg[slot] = ((unsigned long long)u << 28) | (unsigned long long)jc1;
                        }
                    }
                    cnt += __popc(sub1);
                    unsigned long long m2 = __ballot(hit2);
                    unsigned sub2 = (unsigned)((m2 >> gsh) & 0xFFFFull);
                    if (hit2) {
                        int slot = cnt + __popc(sub2 & ((1u << l16) - 1u));
                        if (slot < CAPG) {
                            unsigned u = __float_as_uint(d2);
                            u = (u & 0x80000000u) ? ~u : (u | 0x80000000u);
                            ldg[slot] = ((unsigned long long)u << 28) | (unsigned long long)jc2;
                        }
                    }
                    cnt += __popc(sub2);
                }
            }
        }
        bool bad = active && (cnt < KNN || cnt > CAPG);
        if (__ballot(bad) == 0ULL) break;         // wave-uniform exit
        active = bad;
        if (active) r2 = (cnt < KNN) ? r2 * 1.6f : r2 * 0.82f;
    }

    // sentinels for the 4-wide rank loop
    if (l16 < 4) ldg[cnt + l16] = ~0ULL;

    // fill orig-idx field (bits 14..27) so u64 order == lex (d, orig idx)
    for (int k = l16; k < cnt; k += 16) {
        unsigned long long key = ldg[k];
        int jc = (int)(key & 0x3FFFull);
        ldg[k] = (key & ~0x0FFFFFFFull) | ((unsigned long long)Ob[jc] << 14) | (unsigned long long)jc;
    }
    __builtin_amdgcn_wave_barrier();
    asm volatile("s_waitcnt lgkmcnt(0)" ::: "memory");

    // ---- stable top-30: rank by u64 key, 4-wide vector LDS reads ----
    const double qx = (double)qp.x, qy = (double)qp.y, qz = (double)qp.z;
    double sx = 0.0, sy = 0.0, sz = 0.0;
    double sxx = 0.0, sxy = 0.0, sxz = 0.0, syy = 0.0, syz = 0.0, szz = 0.0;

    const ulonglong2* __restrict__ ldg2 = (const ulonglong2*)ldg;
    const int cntr = (cnt + 3) >> 2;

    for (int k = l16; k < cnt; k += 16) {
        unsigned long long key = ldg[k];
        int rank = 0;
        for (int u = 0; u < cntr; ++u) {
            ulonglong2 a = ldg2[2 * u];
            ulonglong2 c = ldg2[2 * u + 1];
            rank += (a.x < key) ? 1 : 0;
            rank += (a.y < key) ? 1 : 0;
            rank += (c.x < key) ? 1 : 0;
            rank += (c.y < key) ? 1 : 0;
        }
        if (rank < KNN) {
            float4 p = P[(int)(key & 0x3FFFull)];
            double ax = (double)p.x - qx, ay = (double)p.y - qy, az = (double)p.z - qz;
            sx += ax; sy += ay; sz += az;
            sxx = fma(ax, ax, sxx); sxy = fma(ax, ay, sxy); sxz = fma(ax, az, sxz);
            syy = fma(ay, ay, syy); syz = fma(ay, az, syz); szz = fma(az, az, szz);
        }
    }

    #pragma unroll
    for (int off = 1; off < 16; off <<= 1) {
        sx  += __shfl_xor(sx,  off, 16); sy  += __shfl_xor(sy,  off, 16); sz  += __shfl_xor(sz,  off, 16);
        sxx += __shfl_xor(sxx, off, 16); sxy += __shfl_xor(sxy, off, 16); sxz += __shfl_xor(sxz, off, 16);
        syy += __shfl_xor(syy, off, 16); syz += __shfl_xor(syz, off, 16); szz += __shfl_xor(szz, off, 16);
    }

    if (l16 == 0) {
        const double kinv = 1.0 / (double)KNN;
        double m00 = sxx - sx * sx * kinv;
        double m11 = syy - sy * sy * kinv;
        double m22 = szz - sz * sz * kinv;
        double m01 = sxy - sx * sy * kinv;
        double m02 = sxz - sx * sz * kinv;
        double m12 = syz - sy * sz * kinv;

        double nx = 1.0, ny = 0.0, nz = 0.0;
        double q3 = (m00 + m11 + m22) / 3.0;
        double p1 = m01 * m01 + m02 * m02 + m12 * m12;
        double d00 = m00 - q3, d11 = m11 - q3, d22 = m22 - q3;
        double p2 = d00 * d00 + d11 * d11 + d22 * d22 + 2.0 * p1;
        if (p2 > 1e-280) {
            double pp = sqrt(p2 / 6.0);
            double ip = 1.0 / pp;
            double b00 = d00 * ip, b11 = d11 * ip, b22 = d22 * ip;
            double b01 = m01 * ip, b02 = m02 * ip, b12 = m12 * ip;
            double detB = b00 * (b11 * b22 - b12 * b12)
                        - b01 * (b01 * b22 - b12 * b02)
                        + b02 * (b01 * b12 - b11 * b02);
            double rr = 0.5 * detB;
            rr = rr < -1.0 ? -1.0 : (rr > 1.0 ? 1.0 : rr);
            double phi = acos(rr) / 3.0;
            double lam = q3 + 2.0 * pp * cos(phi + 2.0943951023931953); // smallest eig
            double a00 = m00 - lam, a11 = m11 - lam, a22 = m22 - lam;
            double v0x = m01 * m12 - m02 * a11, v0y = m02 * m01 - a00 * m12, v0z = a00 * a11 - m01 * m01;
            double v1x = m01 * a22 - m02 * m12, v1y = m02 * m02 - a00 * a22, v1z = a00 * m12 - m01 * m02;
            double v2x = a11 * a22 - m12 * m12, v2y = m12 * m02 - m01 * a22, v2z = m01 * m12 - a11 * m02;
            double n0 = v0x * v0x + v0y * v0y + v0z * v0z;
            double n1 = v1x * v1x + v1y * v1y + v1z * v1z;
            double n2 = v2x * v2x + v2y * v2y + v2z * v2z;
            double bx = v0x, by = v0y, bz = v0z, bn = n0;
            if (n1 > bn) { bx = v1x; by = v1y; bz = v1z; bn = n1; }
            if (n2 > bn) { bx = v2x; by = v2y; bz = v2z; bn = n2; }
            if (bn > 1e-280) {
                double inv = 1.0 / sqrt(bn);
                nx = bx * inv; ny = by * inv; nz = bz * inv;
            }
        }
        double dq = -(qx * nx + qy * ny + qz * nz);
        if (dq < 0.0) { nx = -nx; ny = -ny; nz = -nz; }

        float* ob = out + (size_t)b * 6 * N_PTS;
        ob[3 * N_PTS + oi] = (float)nx;
        ob[4 * N_PTS + oi] = (float)ny;
        ob[5 * N_PTS + oi] = (float)nz;
    }
}

// ---------------------------------------------------------------------------
// Host-side radius table (input-independent; 8 KB async copy per launch).
// ---------------------------------------------------------------------------
static float  g_r2t[RBINS];
static bool   g_r2t_init = false;

static void build_r2t_host() {
    for (int k = 0; k < RBINS; ++k) {
        double wrep = ((double)k + 0.5) * ((double)RWMAX / (double)RBINS);
        double c = sqrt(wrep); if (c < 1e-3) c = 1e-3;
        double rlo = 0.05, rhi = 6.0;
        for (int it = 0; it < 40; ++it) {
            double r = 0.5 * (rlo + rhi);
            double slo = c - r; if (slo < 0.0) slo = 0.0;
            double h = (c + r - slo) * 0.125;
            double f = 0.0;
            for (int l = 0; l <= 8; ++l) {
                double sq = slo + h * (double)l;
                double cs = c - sq;
                double hh = (r * r - cs * cs) * (0.5 / c);
                double cap = 2.0 * sq;
                if (hh > cap) hh = cap;
                if (hh < 0.0) hh = 0.0;
                double wq = (l == 0 || l == 8) ? 1.0 : ((l & 1) ? 4.0 : 2.0);
                f += wq * exp(-0.5 * sq * sq) * sq * hh;
            }
            double lam = 1089.3 * f * h;
            if (lam < (double)LAMBDA) rlo = r; else rhi = r;
        }
        double rad = rhi * 1.02;
        g_r2t[k] = (float)(rad * rad);
    }
}

// ---------------------------------------------------------------------------
extern "C" void kernel_launch(void* const* d_in, const int* in_sizes, int n_in,
                              void* d_out, int out_size, void* d_ws, size_t ws_size,
                              hipStream_t stream) {
    const float* x = (const float*)d_in[0];
    float* out = (float*)d_out;
    char* ws = (char*)d_ws;
    float4* S    = (float4*)(ws);                 // 512 KB
    int*    O    = (int*)(ws + 524288);           // 128 KB
    int*    bsta = (int*)(ws + 655360);           // 65552 B
    float*  r2t  = (float*)(ws + 720912);         // 8 KB

    if (!g_r2t_init) { build_r2t_host(); g_r2t_init = true; }
    hipMemcpyAsync(r2t, g_r2t, RBINS * sizeof(float), hipMemcpyHostToDevice, stream);

    prep_kernel<<<dim3(4), dim3(1024), 0, stream>>>(x, S, O, bsta, out);
    knn_normal_kernel<<<dim3(32768 / GROUPS), dim3(BLOCK), 0, stream>>>(S, O, bsta, r2t, out);
}